// Round 9
// baseline (311.104 us; speedup 1.0000x reference)
//
#include <hip/hip_runtime.h>
#include <hip/hip_fp16.h>

typedef _Float16 f16;
typedef f16 f16x8 __attribute__((ext_vector_type(8)));
typedef f16 f16x4 __attribute__((ext_vector_type(4)));
typedef float f32x4 __attribute__((ext_vector_type(4)));

constexpr int Bb = 8, Cc = 1024, Tt = 2048, Ci = 512;
constexpr float BN_EPS = 1e-5f;

__device__ __forceinline__ void gload16(const f16* g, f16* l) {
  __builtin_amdgcn_global_load_lds(
      (const __attribute__((address_space(1))) void*)g,
      (__attribute__((address_space(3))) void*)l, 16, 0, 0);
}

// ---------------- fp32 -> fp16 convert (weights) ----------------
__global__ __launch_bounds__(256)
void cvt_kernel(const float* __restrict__ src, f16* __restrict__ dst, int n4) {
  int i = blockIdx.x * blockDim.x + threadIdx.x;
  if (i < n4) {
    float4 v = *((const float4*)src + i);
    f16x4 h;
    h[0] = (f16)v.x; h[1] = (f16)v.y; h[2] = (f16)v.z; h[3] = (f16)v.w;
    *((f16x4*)dst + i) = h;
  }
}

// ---------------- transpose-convert: x[b][c][t] f32 -> xT[b][t][c] f16 ----
__global__ __launch_bounds__(256)
void cvtT_kernel(const float* __restrict__ x, f16* __restrict__ xT) {
  __shared__ float tile[64][68];
  const int b = blockIdx.z, c0 = blockIdx.y * 64, t0 = blockIdx.x * 64;
  const int tid = threadIdx.x;
  const float* xp = x + ((long)b * Cc + c0) * Tt + t0;
  {
    int r = tid >> 4, c4 = (tid & 15) * 4;
    #pragma unroll
    for (int it = 0; it < 4; it++) {
      float4 v = *(const float4*)(xp + (long)(r + it * 16) * Tt + c4);
      *(float4*)&tile[r + it * 16][c4] = v;
    }
  }
  __syncthreads();
  f16* op = xT + ((long)b * Tt + t0) * Cc + c0;
  {
    int c8 = (tid & 7) * 8;
    #pragma unroll
    for (int it = 0; it < 2; it++) {
      int t = (tid >> 3) + it * 32;
      f16x8 o;
      #pragma unroll
      for (int jj = 0; jj < 8; jj++) o[jj] = (f16)tile[c8 + jj][t];
      *(f16x8*)(op + (long)t * Cc + c8) = o;
    }
  }
}

// ======== 256x256 BK=64 GEMM, half-K-phase counted-vmcnt pipeline ==========
// C[m][n] = sum_k A[m][k]*B[n][k]. 8 waves as 2M x 4N (wave tile 128x64).
// LDS: 2 buffers x 64KB, K-major 16B chunks (conflict-free). Phase A of tile
// t issues (t+1).khalf1 -> other buffer; phase B issues (t+2).khalf0 -> the
// just-consumed half of the CURRENT buffer. Steady-state wait: vmcnt(8).
// BIAS_MODE: 0 none, 1 per-m, 2 per-n. DO_MAX: per-column max -> gmax.
template<int BIAS_MODE, bool DO_MAX>
__global__ __launch_bounds__(512, 2)
void gemm256(const f16* __restrict__ A, const f16* __restrict__ B,
             f16* __restrict__ C, const float* __restrict__ bias,
             unsigned* __restrict__ gmax,
             int K, int lda, int ldb, int ldc, long sA, long sB, long sC,
             int nx, int ny)
{
  extern __shared__ f16 lds[];                 // 2 x (16384 A + 16384 B) halves
  // XCD-aware bijective swizzle (grid %8==0), z-major decode
  const int per = gridDim.x >> 3;
  const int nid = (blockIdx.x & 7) * per + (blockIdx.x >> 3);
  const int bz = nid / (nx * ny);
  const int rem = nid - bz * nx * ny;
  const int by = rem / nx, bx = rem - by * nx;

  const int tid = threadIdx.x, lane = tid & 63, wv = tid >> 6;
  const int bm0 = by * 256, bn0 = bx * 256;
  const int wm = wv >> 2, wn = wv & 3;         // 2M x 4N
  const f16* Ab = A + (long)bz * sA + (long)bm0 * lda;
  const f16* Bt = B + (long)bz * sB + (long)bn0 * ldb;
  C += (long)bz * sC;
  const int r16 = lane & 15, khi4 = lane >> 4;
  const int trow = tid & 255, tkq = tid >> 8;

  // stage chunk-pair q (khi = 2q+tkq, rows 0-255), linear LDS dest
  auto stA = [&](int sel, int q, int k0) {
    gload16(Ab + (long)trow * lda + k0 + (2 * q + tkq) * 8,
            lds + sel * 32768 + (q * 512 + wv * 64) * 8);
  };
  auto stB = [&](int sel, int q, int k0) {
    gload16(Bt + (long)trow * ldb + k0 + (2 * q + tkq) * 8,
            lds + sel * 32768 + 16384 + (q * 512 + wv * 64) * 8);
  };

  f32x4 acc[8][4] = {};
  const int nt = K >> 6;
  const int aoff = (khi4 * 256 + wm * 128 + r16) * 8;   // halves
  const int boff = (khi4 * 256 + wn * 64 + r16) * 8;

  // prologue: t0.h0, t0.h1, t1.h0  (12 loads)
  stA(0, 0, 0); stA(0, 1, 0); stB(0, 0, 0); stB(0, 1, 0);
  stA(0, 2, 0); stA(0, 3, 0); stB(0, 2, 0); stB(0, 3, 0);
  stA(1, 0, 64); stA(1, 1, 64); stB(1, 0, 64); stB(1, 1, 64);
  asm volatile("s_waitcnt vmcnt(8)" ::: "memory");      // t0.h0 landed
  __builtin_amdgcn_s_barrier();

  for (int t = 0; t < nt; t++) {
    const int bsel = t & 1, nsel = bsel ^ 1;
    const f16* lA = lds + bsel * 32768;
    const f16* lB = lA + 16384;
    f16x8 a[8], b[4];

    // ---- phase A: issue (t+1).h1 -> nsel; compute K-half0 ----
    if (t + 1 < nt) {
      const int kn = (t + 1) << 6;
      stA(nsel, 2, kn); stA(nsel, 3, kn); stB(nsel, 2, kn); stB(nsel, 3, kn);
    }
    #pragma unroll
    for (int mi = 0; mi < 8; mi++) a[mi] = *(const f16x8*)(lA + aoff + mi * 128);
    #pragma unroll
    for (int nj = 0; nj < 4; nj++) b[nj] = *(const f16x8*)(lB + boff + nj * 128);
    __builtin_amdgcn_s_setprio(1);
    #pragma unroll
    for (int mi = 0; mi < 8; mi++)
      #pragma unroll
      for (int nj = 0; nj < 4; nj++)
        acc[mi][nj] = __builtin_amdgcn_mfma_f32_16x16x32_f16(a[mi], b[nj], acc[mi][nj], 0, 0, 0);
    __builtin_amdgcn_s_setprio(0);
    __builtin_amdgcn_sched_barrier(0);
    if (t + 1 < nt) asm volatile("s_waitcnt vmcnt(8)" ::: "memory");  // t.h1 landed
    else            asm volatile("s_waitcnt vmcnt(0)" ::: "memory");
    __builtin_amdgcn_s_barrier();

    // ---- phase B: issue (t+2).h0 -> bsel.h0 (reads done); compute K-half1 --
    if (t + 2 < nt) {
      const int kn = (t + 2) << 6;
      stA(bsel, 0, kn); stA(bsel, 1, kn); stB(bsel, 0, kn); stB(bsel, 1, kn);
    }
    #pragma unroll
    for (int mi = 0; mi < 8; mi++) a[mi] = *(const f16x8*)(lA + aoff + 8192 + mi * 128);
    #pragma unroll
    for (int nj = 0; nj < 4; nj++) b[nj] = *(const f16x8*)(lB + boff + 8192 + nj * 128);
    __builtin_amdgcn_s_setprio(1);
    #pragma unroll
    for (int mi = 0; mi < 8; mi++)
      #pragma unroll
      for (int nj = 0; nj < 4; nj++)
        acc[mi][nj] = __builtin_amdgcn_mfma_f32_16x16x32_f16(a[mi], b[nj], acc[mi][nj], 0, 0, 0);
    __builtin_amdgcn_s_setprio(0);
    __builtin_amdgcn_sched_barrier(0);
    if (t + 2 < nt)      asm volatile("s_waitcnt vmcnt(8)" ::: "memory"); // (t+1).h0 landed
    else if (t + 1 < nt) asm volatile("s_waitcnt vmcnt(4)" ::: "memory");
    else                 asm volatile("s_waitcnt vmcnt(0)" ::: "memory");
    __builtin_amdgcn_s_barrier();
  }

  // ---- epilogue (fused per-column max for DO_MAX) ----
  const int rg = khi4 * 4;
  float cmx[4] = {-3e38f, -3e38f, -3e38f, -3e38f};
  #pragma unroll
  for (int mi = 0; mi < 8; mi++) {
    const int row0 = bm0 + wm * 128 + mi * 16 + rg;
    #pragma unroll
    for (int r = 0; r < 4; r++) {
      const int row = row0 + r;
      const float br = (BIAS_MODE == 1) ? bias[row] : 0.0f;
      #pragma unroll
      for (int nj = 0; nj < 4; nj++) {
        const int col = bn0 + wn * 64 + nj * 16 + r16;
        float v = acc[mi][nj][r] + ((BIAS_MODE == 2) ? bias[col] : br);
        C[(long)row * ldc + col] = (f16)v;
        if (DO_MAX) cmx[nj] = fmaxf(cmx[nj], v);
      }
    }
  }
  if (DO_MAX) {
    #pragma unroll
    for (int nj = 0; nj < 4; nj++) {
      float mx = cmx[nj];
      mx = fmaxf(mx, __shfl_xor(mx, 16));
      mx = fmaxf(mx, __shfl_xor(mx, 32));
      if (khi4 == 0) {
        const int col = bn0 + wn * 64 + nj * 16 + r16;
        unsigned u = __float_as_uint(mx);
        unsigned key = (u & 0x80000000u) ? ~u : (u | 0x80000000u);
        atomicMax(gmax + (long)bz * ldc + col, key);
      }
    }
  }
}

// ======== r3 256x128 pipelined GEMM (V-proj / PV) ===========================
template<int BIAS_MODE, bool DO_MAX>
__global__ __launch_bounds__(512, 2)
void gemm8p(const f16* __restrict__ A, const f16* __restrict__ B,
            f16* __restrict__ C, const float* __restrict__ bias,
            unsigned* __restrict__ gmax,
            int K, int lda, int ldb, int ldc, long sA, long sB, long sC,
            int nx, int ny)
{
  extern __shared__ f16 lds[];
  constexpr int TILE_A = 256 * 64;
  constexpr int TILE_B = 128 * 64;
  constexpr int TILE   = TILE_A + TILE_B;

  const int per = gridDim.x >> 3;
  const int nid = (blockIdx.x & 7) * per + (blockIdx.x >> 3);
  const int bz = nid / (nx * ny);
  const int rem = nid - bz * nx * ny;
  const int by = rem / nx, bx = rem - by * nx;

  const int tid = threadIdx.x, lane = tid & 63, wv = tid >> 6;
  const int bm0 = by * 256, bn0 = bx * 128;
  const int wm = (wv >> 1) * 64, wn = (wv & 1) * 64;
  const f16* Ab = A + (long)bz * sA + (long)bm0 * lda;
  const f16* Bt = B + (long)bz * sB + (long)bn0 * ldb;
  C += (long)bz * sC;

  const int r16 = lane & 15, khi = lane >> 4;
  const int sw = (r16 & 7) << 4;

  auto stA = [&](int slot, int k0, int r) {
    int L = (r * 512 + tid) * 16;
    int G = L ^ (((L >> 7) & 7) << 4);
    gload16(Ab + (long)(G >> 7) * lda + k0 + ((G & 127) >> 1),
            lds + (long)slot * TILE + (r * 512 + wv * 64) * 8);
  };
  auto stB = [&](int slot, int k0, int r) {
    int L = (r * 512 + tid) * 16;
    int G = L ^ (((L >> 7) & 7) << 4);
    gload16(Bt + (long)(G >> 7) * ldb + k0 + ((G & 127) >> 1),
            lds + (long)slot * TILE + TILE_A + (r * 512 + wv * 64) * 8);
  };

  f32x4 acc[4][4] = {};
  const int nt = K >> 6;

  #pragma unroll
  for (int r = 0; r < 4; r++) stA(0, 0, r);
  #pragma unroll
  for (int r = 0; r < 2; r++) stB(0, 0, r);
  #pragma unroll
  for (int r = 0; r < 4; r++) stA(1, 64, r);
  #pragma unroll
  for (int r = 0; r < 2; r++) stB(1, 64, r);
  asm volatile("s_waitcnt vmcnt(6)" ::: "memory");
  __builtin_amdgcn_s_barrier();

  for (int t = 0; t < nt; t++) {
    const int slot = t % 3;
    const int nslot = (t + 2) % 3;
    const int k2 = (t + 2) << 6;
    const bool st = (t + 2) < nt;
    const char* baseA = (const char*)(lds + (long)slot * TILE);
    const char* baseB = (const char*)(lds + (long)slot * TILE + TILE_A);

    if (st) {
      stA(nslot, k2, 0); stA(nslot, k2, 1); stA(nslot, k2, 2); stA(nslot, k2, 3);
      stB(nslot, k2, 0); stB(nslot, k2, 1);
    }

    f16x8 af0[4], bf0[4], af1[4], bf1[4];
    #pragma unroll
    for (int i = 0; i < 4; i++) {
      af0[i] = *(const f16x8*)(baseA + (((wm + i * 16 + r16) * 128 + khi * 16) ^ sw));
      af1[i] = *(const f16x8*)(baseA + (((wm + i * 16 + r16) * 128 + 64 + khi * 16) ^ sw));
    }
    #pragma unroll
    for (int j = 0; j < 4; j++) {
      bf0[j] = *(const f16x8*)(baseB + (((wn + j * 16 + r16) * 128 + khi * 16) ^ sw));
      bf1[j] = *(const f16x8*)(baseB + (((wn + j * 16 + r16) * 128 + 64 + khi * 16) ^ sw));
    }

    __builtin_amdgcn_s_setprio(1);
    #pragma unroll
    for (int i = 0; i < 4; i++)
      #pragma unroll
      for (int j = 0; j < 4; j++) {
        acc[i][j] = __builtin_amdgcn_mfma_f32_16x16x32_f16(af0[i], bf0[j], acc[i][j], 0, 0, 0);
        acc[i][j] = __builtin_amdgcn_mfma_f32_16x16x32_f16(af1[i], bf1[j], acc[i][j], 0, 0, 0);
      }
    __builtin_amdgcn_s_setprio(0);

    __builtin_amdgcn_sched_barrier(0);
    if (st) asm volatile("s_waitcnt vmcnt(6)" ::: "memory");
    else    asm volatile("s_waitcnt vmcnt(0)" ::: "memory");
    __builtin_amdgcn_s_barrier();
  }

  const int rg = khi * 4;
  float cmx[4] = {-3e38f, -3e38f, -3e38f, -3e38f};
  #pragma unroll
  for (int i = 0; i < 4; i++) {
    const int row0 = bm0 + wm + i * 16 + rg;
    #pragma unroll
    for (int r = 0; r < 4; r++) {
      const int row = row0 + r;
      const float br = (BIAS_MODE == 1) ? bias[row] : 0.0f;
      #pragma unroll
      for (int j = 0; j < 4; j++) {
        const int col = bn0 + wn + j * 16 + r16;
        float v = acc[i][j][r] + ((BIAS_MODE == 2) ? bias[col] : br);
        C[(long)row * ldc + col] = (f16)v;
        if (DO_MAX) cmx[j] = fmaxf(cmx[j], v);
      }
    }
  }
  if (DO_MAX) {
    #pragma unroll
    for (int j = 0; j < 4; j++) {
      float mx = cmx[j];
      mx = fmaxf(mx, __shfl_xor(mx, 16));
      mx = fmaxf(mx, __shfl_xor(mx, 32));
      if (khi == 0) {
        const int col = bn0 + wn + j * 16 + r16;
        unsigned u = __float_as_uint(mx);
        unsigned key = (u & 0x80000000u) ? ~u : (u | 0x80000000u);
        atomicMax(gmax + (long)bz * ldc + col, key);
      }
    }
  }
}

// ---------------- colsum: E = exp(Sq - m[kt]) in place; sums[kt] += ------
__global__ __launch_bounds__(256)
void colsum_kernel(f16* __restrict__ E, const unsigned* __restrict__ gmax,
                   float* __restrict__ sums) {
  const int b = blockIdx.z;
  const int kt = blockIdx.x * 256 + threadIdx.x;
  const long q0 = (long)blockIdx.y * 128;
  unsigned key = gmax[b * Tt + kt];
  float m = (key & 0x80000000u) ? __uint_as_float(key ^ 0x80000000u)
                                : __uint_as_float(~key);
  f16* p = E + ((long)b * Tt + q0) * Tt + kt;
  float s = 0.f;
  #pragma unroll 4
  for (int q = 0; q < 128; q++) {
    float e = __expf((float)p[(long)q * Tt] - m);
    p[(long)q * Tt] = (f16)e;
    s += e;
  }
  atomicAdd(sums + b * Tt + kt, s);
}

// ---------------- vscale: Vt[b][c][kt] *= 1/sums[b][kt] (in place) --------
__global__ __launch_bounds__(256)
void vscale_kernel(f16* __restrict__ Vt, const float* __restrict__ sums) {
  long i = ((long)blockIdx.x * 256 + threadIdx.x) * 8;
  int kt = (int)(i & (Tt - 1));
  int b = (int)(i >> 20);                 // Ci*Tt = 2^20
  f16x8 v = *(f16x8*)(Vt + i);
  const float* sp = sums + b * Tt + kt;
  #pragma unroll
  for (int j = 0; j < 8; j++)
    v[j] = (f16)((float)v[j] * __fdividef(1.0f, sp[j]));
  *(f16x8*)(Vt + i) = v;
}

// ---------------- BN stats per channel over (b,t) --------------------------
__global__ __launch_bounds__(256)
void bnstat_kernel(const f16* __restrict__ wy, float* __restrict__ bsum,
                   float* __restrict__ bsq) {
  const int c = blockIdx.x, tid = threadIdx.x;
  float s1 = 0.f, s2 = 0.f;
  for (int b = 0; b < Bb; b++) {
    f16x8 v = *((const f16x8*)(wy + ((long)b * Cc + c) * Tt) + tid);
    #pragma unroll
    for (int jj = 0; jj < 8; jj++) { float f = (float)v[jj]; s1 += f; s2 += f * f; }
  }
  #pragma unroll
  for (int off = 1; off < 64; off <<= 1) {
    s1 += __shfl_xor(s1, off);
    s2 += __shfl_xor(s2, off);
  }
  __shared__ float l1[4], l2[4];
  const int w = tid >> 6;
  if ((tid & 63) == 0) { l1[w] = s1; l2[w] = s2; }
  __syncthreads();
  if (tid == 0) {
    bsum[c] = (l1[0] + l1[1]) + (l1[2] + l1[3]);
    bsq[c]  = (l2[0] + l2[1]) + (l2[2] + l2[3]);
  }
}

// ---------------- finalize: BN + residual ----------------------------------
__global__ __launch_bounds__(256)
void final_kernel(const f16* __restrict__ wy, const float* __restrict__ x,
                  const float* __restrict__ gamma, const float* __restrict__ beta,
                  const float* __restrict__ bsum, const float* __restrict__ bsq,
                  float* __restrict__ out)
{
  long i = ((long)blockIdx.x * blockDim.x + threadIdx.x) * 4;
  int c = (int)((i >> 11) & (Cc - 1));
  const float cnt = (float)Bb * (float)Tt;
  float mean = bsum[c] / cnt;
  float var  = bsq[c] / cnt - mean * mean;
  float sc = rsqrtf(var + BN_EPS) * gamma[c];
  float sh = beta[c] - mean * sc;
  f16x4 w = *(const f16x4*)(wy + i);
  float4 xv = *(const float4*)(x + i);
  float4 o;
  o.x = (float)w[0] * sc + sh + xv.x;
  o.y = (float)w[1] * sc + sh + xv.y;
  o.z = (float)w[2] * sc + sh + xv.z;
  o.w = (float)w[3] * sc + sh + xv.w;
  *(float4*)(out + i) = o;
}

// ---------------- host launch ----------------
extern "C" void kernel_launch(void* const* d_in, const int* in_sizes, int n_in,
                              void* d_out, int out_size, void* d_ws, size_t ws_size,
                              hipStream_t stream) {
  const float* x    = (const float*)d_in[0];
  const float* Wq_w = (const float*)d_in[1];
  const float* Wq_b = (const float*)d_in[2];
  const float* Wk_w = (const float*)d_in[3];
  const float* Wk_b = (const float*)d_in[4];
  const float* Wv_w = (const float*)d_in[5];
  const float* Wv_b = (const float*)d_in[6];
  const float* Wo_w = (const float*)d_in[7];
  const float* Wo_b = (const float*)d_in[8];
  const float* gamma = (const float*)d_in[9];
  const float* beta  = (const float*)d_in[10];
  float* out = (float*)d_out;

  constexpr long SZ_XT = (long)Bb * Tt * Cc;   // 16,777,216
  constexpr long SZ_Q  = (long)Bb * Tt * Ci;   // 8,388,608
  constexpr long SZ_S  = (long)Bb * Tt * Tt;   // 33,554,432
  constexpr long SZ_W  = (long)Ci * Cc;        // 524,288

  f16* ws = (f16*)d_ws;
  f16* xT  = ws;                // [B][T][C]
  f16* QK  = xT + SZ_XT;        // [B][T][1024]: Q cols 0-511, K cols 512-1023
  f16* Vt  = QK + SZ_XT;        // [B][Ci][T]
  f16* Sq  = Vt + SZ_Q;         // [B][Tq][Tk] -> exp'd in place by colsum
  f16* Y   = Sq + SZ_S;         // [B][Tq][Ci]
  f16* wy  = Y + SZ_Q;          // [B][C][T]
  f16* wqk = wy + SZ_XT;        // [1024][1024] stacked Wq||Wk
  f16* wv  = wqk + 2 * SZ_W;
  f16* wo  = wv + SZ_W;
  unsigned* gmax = (unsigned*)(wo + SZ_W);     // [B*Tt] encoded col max
  float* sums = (float*)(gmax + (long)Bb * Tt);// [B*Tt]
  float* bsum = sums + (long)Bb * Tt;          // [Cc]
  float* bsq  = bsum + Cc;                     // [Cc]
  float* qkb  = bsq + Cc;                      // [1024] concat bias

  constexpr int LDSB  = (256 * 64 + 128 * 64) * 3 * 2; // 147456 B (gemm8p)
  constexpr int LDSB2 = 2 * 32768 * 2;                 // 131072 B (gemm256)
  hipFuncSetAttribute(reinterpret_cast<const void*>(gemm256<2, false>),
                      hipFuncAttributeMaxDynamicSharedMemorySize, LDSB2);
  hipFuncSetAttribute(reinterpret_cast<const void*>(gemm256<1, false>),
                      hipFuncAttributeMaxDynamicSharedMemorySize, LDSB2);
  hipFuncSetAttribute(reinterpret_cast<const void*>(gemm256<0, true>),
                      hipFuncAttributeMaxDynamicSharedMemorySize, LDSB2);
  hipFuncSetAttribute(reinterpret_cast<const void*>(gemm8p<1, false>),
                      hipFuncAttributeMaxDynamicSharedMemorySize, LDSB);
  hipFuncSetAttribute(reinterpret_cast<const void*>(gemm8p<0, false>),
                      hipFuncAttributeMaxDynamicSharedMemorySize, LDSB);

  // zero accumulators (gmax||sums contiguous)
  hipMemsetAsync(gmax, 0, (long)Bb * Tt * 2 * sizeof(float), stream);
  // concat q/k bias
  hipMemcpyAsync(qkb, Wq_b, Ci * sizeof(float), hipMemcpyDeviceToDevice, stream);
  hipMemcpyAsync(qkb + Ci, Wk_b, Ci * sizeof(float), hipMemcpyDeviceToDevice, stream);

  // weight converts (wq||wk stacked)
  cvt_kernel<<<(int)(SZ_W / 4 / 256), 256, 0, stream>>>(Wq_w, wqk, (int)(SZ_W / 4));
  cvt_kernel<<<(int)(SZ_W / 4 / 256), 256, 0, stream>>>(Wk_w, wqk + SZ_W, (int)(SZ_W / 4));
  cvt_kernel<<<(int)(SZ_W / 4 / 256), 256, 0, stream>>>(Wv_w, wv, (int)(SZ_W / 4));
  cvt_kernel<<<(int)(SZ_W / 4 / 256), 256, 0, stream>>>(Wo_w, wo, (int)(SZ_W / 4));
  // x transpose-convert
  cvtT_kernel<<<dim3(Tt / 64, Cc / 64, Bb), 256, 0, stream>>>(x, xT);

  // fused QK projection: QK[t][o] = sum_c xT[t][c] wqk[o][c] + qkb[o]
  gemm256<2, false><<<4 * 8 * Bb, 512, LDSB2, stream>>>(
      xT, wqk, QK, qkb, nullptr,
      Cc, Cc, Cc, 1024, (long)Tt * Cc, 0, (long)Tt * 1024, 4, 8);

  // Vt[o][t] = sum_c Wv[o][c] xT[t][c] + bv[o]
  gemm8p<1, false><<<16 * 2 * Bb, 512, LDSB, stream>>>(
      wv, xT, Vt, Wv_b, nullptr,
      Cc, Cc, Cc, Tt, 0, (long)Tt * Cc, (long)Ci * Tt, 16, 2);

  // Sq[q][kt] = sum_c Q[q][c] K[kt][c]  (+ fused per-kt max)
  gemm256<0, true><<<8 * 8 * Bb, 512, LDSB2, stream>>>(
      QK, QK + 512, Sq, nullptr, gmax,
      Ci, 1024, 1024, Tt, (long)Tt * 1024, (long)Tt * 1024, (long)Tt * Tt, 8, 8);

  // E = exp(Sq - m[kt]) in place + per-kt sums
  colsum_kernel<<<dim3(Tt / 256, Tt / 128, Bb), 256, 0, stream>>>(Sq, gmax, sums);

  // fold 1/sum into V
  vscale_kernel<<<(int)(SZ_Q / 8 / 256), 256, 0, stream>>>(Vt, sums);

  // Y[q][c] = sum_kt E[q][kt] Vs[c][kt]
  gemm8p<0, false><<<4 * 8 * Bb, 512, LDSB, stream>>>(
      Sq, Vt, Y, nullptr, nullptr,
      Tt, Tt, Tt, Ci, (long)Tt * Tt, (long)Ci * Tt, (long)Tt * Ci, 4, 8);

  // wy[o][t] = sum_c Wo[o][c] Y[t][c] + bo[o]
  gemm256<1, false><<<8 * 4 * Bb, 512, LDSB2, stream>>>(
      wo, Y, wy, Wo_b, nullptr,
      Ci, Ci, Ci, Tt, 0, (long)Tt * Ci, (long)Cc * Tt, 8, 4);

  // BN stats + finalize
  bnstat_kernel<<<Cc, 256, 0, stream>>>(wy, bsum, bsq);
  final_kernel<<<(int)(SZ_XT / 4 / 256), 256, 0, stream>>>(
      wy, x, gamma, beta, bsum, bsq, out);
}

// Round 10
// 271.729 us; speedup vs baseline: 1.1449x; 1.1449x over previous
//
#include <hip/hip_runtime.h>
#include <hip/hip_fp16.h>

typedef _Float16 f16;
typedef f16 f16x8 __attribute__((ext_vector_type(8)));
typedef f16 f16x4 __attribute__((ext_vector_type(4)));
typedef float f32x4 __attribute__((ext_vector_type(4)));

constexpr int Bb = 8, Cc = 1024, Tt = 2048, Ci = 512;
constexpr float BN_EPS = 1e-5f;

__device__ __forceinline__ void gload16(const f16* g, f16* l) {
  __builtin_amdgcn_global_load_lds(
      (const __attribute__((address_space(1))) void*)g,
      (__attribute__((address_space(3))) void*)l, 16, 0, 0);
}

// ---------------- fp32 -> fp16 convert (weights) ----------------
__global__ __launch_bounds__(256)
void cvt_kernel(const float* __restrict__ src, f16* __restrict__ dst, int n4) {
  int i = blockIdx.x * blockDim.x + threadIdx.x;
  if (i < n4) {
    float4 v = *((const float4*)src + i);
    f16x4 h;
    h[0] = (f16)v.x; h[1] = (f16)v.y; h[2] = (f16)v.z; h[3] = (f16)v.w;
    *((f16x4*)dst + i) = h;
  }
}

// ---------------- transpose-convert: x[b][c][t] f32 -> xT[b][t][c] f16 ----
__global__ __launch_bounds__(256)
void cvtT_kernel(const float* __restrict__ x, f16* __restrict__ xT) {
  __shared__ float tile[64][68];
  const int b = blockIdx.z, c0 = blockIdx.y * 64, t0 = blockIdx.x * 64;
  const int tid = threadIdx.x;
  const float* xp = x + ((long)b * Cc + c0) * Tt + t0;
  {
    int r = tid >> 4, c4 = (tid & 15) * 4;
    #pragma unroll
    for (int it = 0; it < 4; it++) {
      float4 v = *(const float4*)(xp + (long)(r + it * 16) * Tt + c4);
      *(float4*)&tile[r + it * 16][c4] = v;
    }
  }
  __syncthreads();
  f16* op = xT + ((long)b * Tt + t0) * Cc + c0;
  {
    int c8 = (tid & 7) * 8;
    #pragma unroll
    for (int it = 0; it < 2; it++) {
      int t = (tid >> 3) + it * 32;
      f16x8 o;
      #pragma unroll
      for (int jj = 0; jj < 8; jj++) o[jj] = (f16)tile[c8 + jj][t];
      *(f16x8*)(op + (long)t * Cc + c8) = o;
    }
  }
}

// ======== 256x128 BK=32 ring-3 GEMM (2 blocks/CU) + XCD swizzle ============
// C[m][n] = sum_k A[m][k]*B[n][k]; A:[M,K](lda), B:[N,K](ldb), C:[M,N](ldc).
// LDS 24KB/slot x 3 = 72KB -> 2 blocks/CU (16 waves, cross-block overlap
// hides the per-tile vmcnt+barrier drain). Counted vmcnt(3) steady-state
// (prefetch distance 2 tiles). XOR involution (slot[5:4] ^= row[8:7]) on
// BOTH stage-source and ds_read: 16-lane frag read = 8 bank-quads x 2-way.
// BIAS_MODE: 0 none, 1 per-m, 2 per-n. DO_MAX: per-column max -> gmax.
template<int BIAS_MODE, bool DO_MAX>
__global__ __launch_bounds__(512, 2)
void gemm8p(const f16* __restrict__ A, const f16* __restrict__ B,
            f16* __restrict__ C, const float* __restrict__ bias,
            unsigned* __restrict__ gmax,
            int K, int lda, int ldb, int ldc, long sA, long sB, long sC,
            int nx, int ny)
{
  extern __shared__ f16 lds[];
  constexpr int TILE_A = 256 * 32;           // 8192 halves (16 KB)
  constexpr int TILE_B = 128 * 32;           // 4096 halves (8 KB)
  constexpr int TILE   = TILE_A + TILE_B;    // 12288 halves (24 KB)

  // XCD-aware bijective swizzle (grid %8==0), z-major decode
  const int per = gridDim.x >> 3;
  const int nid = (blockIdx.x & 7) * per + (blockIdx.x >> 3);
  const int bz = nid / (nx * ny);
  const int rem = nid - bz * nx * ny;
  const int by = rem / nx, bx = rem - by * nx;

  const int tid = threadIdx.x, lane = tid & 63, wv = tid >> 6;
  const int bm0 = by * 256, bn0 = bx * 128;
  const int wm = (wv >> 1) * 64, wn = (wv & 1) * 64;
  const f16* Ab = A + (long)bz * sA + (long)bm0 * lda;
  const f16* Bt = B + (long)bz * sB + (long)bn0 * ldb;
  C += (long)bz * sC;

  const int r16 = lane & 15, khi = lane >> 4;

  // stage: linear LDS dest (wave-uniform base + lane*16), pre-swizzled src.
  // chunk byte L -> source byte G = L ^ ((L>>7 & 3) << 4)  (row bits 1..2
  // XOR'd into 16B-slot bits). row = G>>6, k-offset halves = (G&63)>>1.
  auto stA = [&](int slot, int k0, int r) {
    int L = (r * 512 + tid) * 16;
    int G = L ^ (((L >> 7) & 3) << 4);
    gload16(Ab + (long)(G >> 6) * lda + k0 + ((G & 63) >> 1),
            lds + (long)slot * TILE + (r * 512 + wv * 64) * 8);
  };
  auto stB = [&](int slot, int k0) {
    int L = tid * 16;
    int G = L ^ (((L >> 7) & 3) << 4);
    gload16(Bt + (long)(G >> 6) * ldb + k0 + ((G & 63) >> 1),
            lds + (long)slot * TILE + TILE_A + (wv * 64) * 8);
  };

  f32x4 acc[4][4] = {};
  const int nt = K >> 5;

  // prologue: tiles 0 and 1 (3 loads each)
  stA(0, 0, 0); stA(0, 0, 1); stB(0, 0);
  stA(1, 32, 0); stA(1, 32, 1); stB(1, 32);
  asm volatile("s_waitcnt vmcnt(3)" ::: "memory");   // tile0 landed
  __builtin_amdgcn_s_barrier();

  for (int t = 0; t < nt; t++) {
    const int slot = t % 3;
    const int nslot = (t + 2) % 3;
    const int k2 = (t + 2) << 5;
    const bool st = (t + 2) < nt;
    const char* baseA = (const char*)(lds + (long)slot * TILE);
    const char* baseB = (const char*)(lds + (long)slot * TILE + TILE_A);

    if (st) { stA(nslot, k2, 0); stA(nslot, k2, 1); stB(nslot, k2); }

    f16x8 af[4], bf[4];
    #pragma unroll
    for (int i = 0; i < 4; i++) {
      const int row = wm + i * 16 + r16;
      af[i] = *(const f16x8*)(baseA + (((row << 6) + (khi << 4)) ^ (((row >> 1) & 3) << 4)));
    }
    #pragma unroll
    for (int j = 0; j < 4; j++) {
      const int row = wn + j * 16 + r16;
      bf[j] = *(const f16x8*)(baseB + (((row << 6) + (khi << 4)) ^ (((row >> 1) & 3) << 4)));
    }

    __builtin_amdgcn_s_setprio(1);
    #pragma unroll
    for (int i = 0; i < 4; i++)
      #pragma unroll
      for (int j = 0; j < 4; j++)
        acc[i][j] = __builtin_amdgcn_mfma_f32_16x16x32_f16(af[i], bf[j], acc[i][j], 0, 0, 0);
    __builtin_amdgcn_s_setprio(0);

    __builtin_amdgcn_sched_barrier(0);
    if (st) asm volatile("s_waitcnt vmcnt(3)" ::: "memory");
    else    asm volatile("s_waitcnt vmcnt(0)" ::: "memory");
    __builtin_amdgcn_s_barrier();
  }

  // ---- epilogue (fused per-column max for DO_MAX) ----
  const int rg = khi * 4;
  float cmx[4] = {-3e38f, -3e38f, -3e38f, -3e38f};
  #pragma unroll
  for (int i = 0; i < 4; i++) {
    const int row0 = bm0 + wm + i * 16 + rg;
    #pragma unroll
    for (int r = 0; r < 4; r++) {
      const int row = row0 + r;
      const float br = (BIAS_MODE == 1) ? bias[row] : 0.0f;
      #pragma unroll
      for (int j = 0; j < 4; j++) {
        const int col = bn0 + wn + j * 16 + r16;
        float v = acc[i][j][r] + ((BIAS_MODE == 2) ? bias[col] : br);
        C[(long)row * ldc + col] = (f16)v;
        if (DO_MAX) cmx[j] = fmaxf(cmx[j], v);
      }
    }
  }
  if (DO_MAX) {
    #pragma unroll
    for (int j = 0; j < 4; j++) {
      float mx = cmx[j];
      mx = fmaxf(mx, __shfl_xor(mx, 16));
      mx = fmaxf(mx, __shfl_xor(mx, 32));
      if (khi == 0) {
        const int col = bn0 + wn + j * 16 + r16;
        unsigned u = __float_as_uint(mx);
        unsigned key = (u & 0x80000000u) ? ~u : (u | 0x80000000u);
        atomicMax(gmax + (long)bz * ldc + col, key);
      }
    }
  }
}

// ---------------- colsum: E = exp(Sq - m[kt]) in place; sums[kt] += ------
__global__ __launch_bounds__(256)
void colsum_kernel(f16* __restrict__ E, const unsigned* __restrict__ gmax,
                   float* __restrict__ sums) {
  const int b = blockIdx.z;
  const int kt = blockIdx.x * 256 + threadIdx.x;
  const long q0 = (long)blockIdx.y * 128;
  unsigned key = gmax[b * Tt + kt];
  float m = (key & 0x80000000u) ? __uint_as_float(key ^ 0x80000000u)
                                : __uint_as_float(~key);
  f16* p = E + ((long)b * Tt + q0) * Tt + kt;
  float s = 0.f;
  #pragma unroll 4
  for (int q = 0; q < 128; q++) {
    float e = __expf((float)p[(long)q * Tt] - m);
    p[(long)q * Tt] = (f16)e;
    s += e;
  }
  atomicAdd(sums + b * Tt + kt, s);
}

// ---------------- vscale: Vt[b][c][kt] *= 1/sums[b][kt] (in place) --------
__global__ __launch_bounds__(256)
void vscale_kernel(f16* __restrict__ Vt, const float* __restrict__ sums) {
  long i = ((long)blockIdx.x * 256 + threadIdx.x) * 8;
  int kt = (int)(i & (Tt - 1));
  int b = (int)(i >> 20);                 // Ci*Tt = 2^20
  f16x8 v = *(f16x8*)(Vt + i);
  const float* sp = sums + b * Tt + kt;
  #pragma unroll
  for (int j = 0; j < 8; j++)
    v[j] = (f16)((float)v[j] * __fdividef(1.0f, sp[j]));
  *(f16x8*)(Vt + i) = v;
}

// ---------------- BN stats per channel over (b,t) --------------------------
__global__ __launch_bounds__(256)
void bnstat_kernel(const f16* __restrict__ wy, float* __restrict__ bsum,
                   float* __restrict__ bsq) {
  const int c = blockIdx.x, tid = threadIdx.x;
  float s1 = 0.f, s2 = 0.f;
  for (int b = 0; b < Bb; b++) {
    f16x8 v = *((const f16x8*)(wy + ((long)b * Cc + c) * Tt) + tid);
    #pragma unroll
    for (int jj = 0; jj < 8; jj++) { float f = (float)v[jj]; s1 += f; s2 += f * f; }
  }
  #pragma unroll
  for (int off = 1; off < 64; off <<= 1) {
    s1 += __shfl_xor(s1, off);
    s2 += __shfl_xor(s2, off);
  }
  __shared__ float l1[4], l2[4];
  const int w = tid >> 6;
  if ((tid & 63) == 0) { l1[w] = s1; l2[w] = s2; }
  __syncthreads();
  if (tid == 0) {
    bsum[c] = (l1[0] + l1[1]) + (l1[2] + l1[3]);
    bsq[c]  = (l2[0] + l2[1]) + (l2[2] + l2[3]);
  }
}

// ---------------- finalize: BN + residual ----------------------------------
__global__ __launch_bounds__(256)
void final_kernel(const f16* __restrict__ wy, const float* __restrict__ x,
                  const float* __restrict__ gamma, const float* __restrict__ beta,
                  const float* __restrict__ bsum, const float* __restrict__ bsq,
                  float* __restrict__ out)
{
  long i = ((long)blockIdx.x * blockDim.x + threadIdx.x) * 4;
  int c = (int)((i >> 11) & (Cc - 1));
  const float cnt = (float)Bb * (float)Tt;
  float mean = bsum[c] / cnt;
  float var  = bsq[c] / cnt - mean * mean;
  float sc = rsqrtf(var + BN_EPS) * gamma[c];
  float sh = beta[c] - mean * sc;
  f16x4 w = *(const f16x4*)(wy + i);
  float4 xv = *(const float4*)(x + i);
  float4 o;
  o.x = (float)w[0] * sc + sh + xv.x;
  o.y = (float)w[1] * sc + sh + xv.y;
  o.z = (float)w[2] * sc + sh + xv.z;
  o.w = (float)w[3] * sc + sh + xv.w;
  *(float4*)(out + i) = o;
}

// ---------------- host launch ----------------
extern "C" void kernel_launch(void* const* d_in, const int* in_sizes, int n_in,
                              void* d_out, int out_size, void* d_ws, size_t ws_size,
                              hipStream_t stream) {
  const float* x    = (const float*)d_in[0];
  const float* Wq_w = (const float*)d_in[1];
  const float* Wq_b = (const float*)d_in[2];
  const float* Wk_w = (const float*)d_in[3];
  const float* Wk_b = (const float*)d_in[4];
  const float* Wv_w = (const float*)d_in[5];
  const float* Wv_b = (const float*)d_in[6];
  const float* Wo_w = (const float*)d_in[7];
  const float* Wo_b = (const float*)d_in[8];
  const float* gamma = (const float*)d_in[9];
  const float* beta  = (const float*)d_in[10];
  float* out = (float*)d_out;

  constexpr long SZ_XT = (long)Bb * Tt * Cc;   // 16,777,216
  constexpr long SZ_Q  = (long)Bb * Tt * Ci;   // 8,388,608
  constexpr long SZ_S  = (long)Bb * Tt * Tt;   // 33,554,432
  constexpr long SZ_W  = (long)Ci * Cc;        // 524,288

  f16* ws = (f16*)d_ws;
  f16* xT  = ws;                // [B][T][C]
  f16* QK  = xT + SZ_XT;        // [B][T][1024]: Q cols 0-511, K cols 512-1023
  f16* Vt  = QK + SZ_XT;        // [B][Ci][T]
  f16* Sq  = Vt + SZ_Q;         // [B][Tq][Tk] -> exp'd in place by colsum
  f16* Y   = Sq + SZ_S;         // [B][Tq][Ci]
  f16* wy  = Y + SZ_Q;          // [B][C][T]
  f16* wqk = wy + SZ_XT;        // [1024][1024] stacked Wq||Wk
  f16* wv  = wqk + 2 * SZ_W;
  f16* wo  = wv + SZ_W;
  unsigned* gmax = (unsigned*)(wo + SZ_W);     // [B*Tt] encoded col max
  float* sums = (float*)(gmax + (long)Bb * Tt);// [B*Tt]
  float* bsum = sums + (long)Bb * Tt;          // [Cc]
  float* bsq  = bsum + Cc;                     // [Cc]
  float* qkb  = bsq + Cc;                      // [1024] concat bias

  constexpr int LDSB = (256 * 32 + 128 * 32) * 3 * 2; // 73728 B -> 2 blocks/CU
  hipFuncSetAttribute(reinterpret_cast<const void*>(gemm8p<2, false>),
                      hipFuncAttributeMaxDynamicSharedMemorySize, LDSB);
  hipFuncSetAttribute(reinterpret_cast<const void*>(gemm8p<1, false>),
                      hipFuncAttributeMaxDynamicSharedMemorySize, LDSB);
  hipFuncSetAttribute(reinterpret_cast<const void*>(gemm8p<0, true>),
                      hipFuncAttributeMaxDynamicSharedMemorySize, LDSB);
  hipFuncSetAttribute(reinterpret_cast<const void*>(gemm8p<0, false>),
                      hipFuncAttributeMaxDynamicSharedMemorySize, LDSB);

  // zero accumulators (gmax||sums contiguous)
  hipMemsetAsync(gmax, 0, (long)Bb * Tt * 2 * sizeof(float), stream);
  // concat q/k bias
  hipMemcpyAsync(qkb, Wq_b, Ci * sizeof(float), hipMemcpyDeviceToDevice, stream);
  hipMemcpyAsync(qkb + Ci, Wk_b, Ci * sizeof(float), hipMemcpyDeviceToDevice, stream);

  // weight converts (wq||wk stacked)
  cvt_kernel<<<(int)(SZ_W / 4 / 256), 256, 0, stream>>>(Wq_w, wqk, (int)(SZ_W / 4));
  cvt_kernel<<<(int)(SZ_W / 4 / 256), 256, 0, stream>>>(Wk_w, wqk + SZ_W, (int)(SZ_W / 4));
  cvt_kernel<<<(int)(SZ_W / 4 / 256), 256, 0, stream>>>(Wv_w, wv, (int)(SZ_W / 4));
  cvt_kernel<<<(int)(SZ_W / 4 / 256), 256, 0, stream>>>(Wo_w, wo, (int)(SZ_W / 4));
  // x transpose-convert
  cvtT_kernel<<<dim3(Tt / 64, Cc / 64, Bb), 256, 0, stream>>>(x, xT);

  // fused QK projection: QK[t][o] = sum_c xT[t][c] wqk[o][c] + qkb[o]
  gemm8p<2, false><<<8 * 8 * Bb, 512, LDSB, stream>>>(
      xT, wqk, QK, qkb, nullptr,
      Cc, Cc, Cc, 1024, (long)Tt * Cc, 0, (long)Tt * 1024, 8, 8);

  // Vt[o][t] = sum_c Wv[o][c] xT[t][c] + bv[o]
  gemm8p<1, false><<<16 * 2 * Bb, 512, LDSB, stream>>>(
      wv, xT, Vt, Wv_b, nullptr,
      Cc, Cc, Cc, Tt, 0, (long)Tt * Cc, (long)Ci * Tt, 16, 2);

  // Sq[q][kt] = sum_c Q[q][c] K[kt][c]  (+ fused per-kt max)
  gemm8p<0, true><<<16 * 8 * Bb, 512, LDSB, stream>>>(
      QK, QK + 512, Sq, nullptr, gmax,
      Ci, 1024, 1024, Tt, (long)Tt * 1024, (long)Tt * 1024, (long)Tt * Tt, 16, 8);

  // E = exp(Sq - m[kt]) in place + per-kt sums
  colsum_kernel<<<dim3(Tt / 256, Tt / 128, Bb), 256, 0, stream>>>(Sq, gmax, sums);

  // fold 1/sum into V
  vscale_kernel<<<(int)(SZ_Q / 8 / 256), 256, 0, stream>>>(Vt, sums);

  // Y[q][c] = sum_kt E[q][kt] Vs[c][kt]
  gemm8p<0, false><<<4 * 8 * Bb, 512, LDSB, stream>>>(
      Sq, Vt, Y, nullptr, nullptr,
      Tt, Tt, Tt, Ci, (long)Tt * Tt, (long)Ci * Tt, (long)Tt * Ci, 4, 8);

  // wy[o][t] = sum_c Wo[o][c] Y[t][c] + bo[o]
  gemm8p<1, false><<<16 * 4 * Bb, 512, LDSB, stream>>>(
      wo, Y, wy, Wo_b, nullptr,
      Ci, Ci, Ci, Tt, 0, (long)Tt * Ci, (long)Cc * Tt, 16, 4);

  // BN stats + finalize
  bnstat_kernel<<<Cc, 256, 0, stream>>>(wy, bsum, bsq);
  final_kernel<<<(int)(SZ_XT / 4 / 256), 256, 0, stream>>>(
      wy, x, gamma, beta, bsum, bsq, out);
}